// Round 6
// baseline (747.152 us; speedup 1.0000x reference)
//
#include <hip/hip_runtime.h>

// GCN 2-layer, CSR-gather version. N=100000, E=3200000, F=512, H=16, C=40.
// Round-3 profile: 51.2M fp32 scatter-atomics/pass => 205MB HBM write-through
// each (350us total); gemm1 broadcast-scalar loads => 175us. Fix: device-built
// CSR (count/scan/fill, atomics once) + gather-side aggregation (no fp32
// atomics, out written once), and LDS-staged gemm1 with b128 reads.

#define NF 512
#define NH 16
#define XPAD 520   // 16-row x tile padded: row r starts at bank (8r)%32

// ---- ws layout (4B units) ----
// wdeg/dinv @ 0          (n)
// ideg      @ 100000     (n)
// rowptr    @ 200000     (n+1)
// cursor    @ 300008     (n)
// bsum      @ 400016     (nblk+1)
// csr(int2) @ 401024     (2*E)   8B aligned: 401024*4 % 8 == 0
// h         @ 6801024    (n*16)
// o1        @ 8401024    (n*16)
// o2        @ 10001024   (n*16)

__global__ __launch_bounds__(256) void k_init(float* __restrict__ wdeg,
                                              int* __restrict__ ideg,
                                              int* __restrict__ cursor, int n) {
    int i = blockIdx.x * 256 + threadIdx.x;
    if (i < n) { wdeg[i] = 1.0f; ideg[i] = 0; cursor[i] = 0; }
}

__global__ __launch_bounds__(256) void k_count(const int* __restrict__ dst,
                                               const float* __restrict__ ew,
                                               int* __restrict__ ideg,
                                               float* __restrict__ wdeg, int E) {
    int e = blockIdx.x * 256 + threadIdx.x;
    if (e < E) {
        int d = dst[e];
        atomicAdd(&ideg[d], 1);
        unsafeAtomicAdd(&wdeg[d], ew[e]);
    }
}

__global__ __launch_bounds__(256) void k_dinv(float* __restrict__ wdeg, int n) {
    int i = blockIdx.x * 256 + threadIdx.x;
    if (i < n) wdeg[i] = rsqrtf(wdeg[i]);   // wdeg >= 1
}

// exclusive scan of ideg -> rowptr, two-level
__global__ __launch_bounds__(256) void k_scan_block(const int* __restrict__ ideg,
                                                    int* __restrict__ rowptr,
                                                    int* __restrict__ bsum, int n) {
    __shared__ int sh[256];
    int t = threadIdx.x, g = blockIdx.x * 256 + t;
    int v = (g < n) ? ideg[g] : 0;
    sh[t] = v; __syncthreads();
    for (int off = 1; off < 256; off <<= 1) {
        int a = (t >= off) ? sh[t - off] : 0;
        __syncthreads();
        sh[t] += a;
        __syncthreads();
    }
    if (g < n) rowptr[g] = sh[t] - v;
    if (t == 255) bsum[blockIdx.x] = sh[255];
}

__global__ __launch_bounds__(512) void k_scan_tops(int* __restrict__ bsum,
                                                   int* __restrict__ rowptr,
                                                   int nb, int n) {
    __shared__ int sh[512];
    int t = threadIdx.x;
    int v = (t < nb) ? bsum[t] : 0;
    sh[t] = v; __syncthreads();
    for (int off = 1; off < 512; off <<= 1) {
        int a = (t >= off) ? sh[t - off] : 0;
        __syncthreads();
        sh[t] += a;
        __syncthreads();
    }
    if (t < nb) bsum[t] = sh[t] - v;       // exclusive
    if (t == 511) rowptr[n] = sh[511];     // == E
}

__global__ __launch_bounds__(256) void k_scan_add(int* __restrict__ rowptr,
                                                  const int* __restrict__ bsum, int n) {
    int i = blockIdx.x * 256 + threadIdx.x;
    if (i < n) rowptr[i] += bsum[i >> 8];
}

__global__ __launch_bounds__(256) void k_fill(const int* __restrict__ src,
                                              const int* __restrict__ dst,
                                              const float* __restrict__ ew,
                                              const float* __restrict__ dinv,
                                              const int* __restrict__ rowptr,
                                              int* __restrict__ cursor,
                                              int2* __restrict__ csr, int E) {
    int e = blockIdx.x * 256 + threadIdx.x;
    if (e >= E) return;
    int s = src[e], d = dst[e];
    float nrm = dinv[s] * ew[e] * dinv[d];
    int pos = rowptr[d] + atomicAdd(&cursor[d], 1);
    csr[pos] = make_int2(s, __float_as_int(nrm));
}

// h = x @ W1, 16 rows per block. x tile LDS-staged via coalesced float4;
// W1 in k4-blocked LDS layout wt[k4][f][4]: the 16-lane b128 read covers 64
// consecutive floats = 2 lanes/bank = conflict-free with zero padding.
__global__ __launch_bounds__(256) void k_gemm1(const float* __restrict__ x,
                                               const float* __restrict__ w1,
                                               float* __restrict__ h) {
    __shared__ float xs[16 * XPAD];
    __shared__ float wt[NF * NH];     // blocked: [(k>>2)][f][k&3]
    for (int t = threadIdx.x; t < NF * NH; t += 256) {
        int k = t >> 4, f = t & 15;
        wt[(k >> 2) * 64 + (f << 2) + (k & 3)] = w1[t];
    }
    // stage 16 contiguous rows of x as float4
    const float4* xsrc = (const float4*)(x + (size_t)blockIdx.x * 16 * NF);
#pragma unroll
    for (int s = 0; s < 8; ++s) {
        int idx = s * 256 + threadIdx.x;      // float4 index within 16x512 tile
        int row = idx >> 7, col4 = idx & 127; // 128 float4 per row
        float4 v = xsrc[idx];
        float* p = &xs[row * XPAD + col4 * 4];
        p[0] = v.x; p[1] = v.y; p[2] = v.z; p[3] = v.w;
    }
    __syncthreads();
    int r = threadIdx.x >> 4, f = threadIdx.x & 15;
    const float4* xr = (const float4*)&xs[r * XPAD];
    const float4* wr = (const float4*)&wt[f << 2];   // stride 16 float4 per k4
    float acc = 0.0f;
#pragma unroll 8
    for (int k4 = 0; k4 < NF / 4; ++k4) {
        float4 a = xr[k4], b = wr[k4 * 16];
        acc = fmaf(a.x, b.x, acc);
        acc = fmaf(a.y, b.y, acc);
        acc = fmaf(a.z, b.z, acc);
        acc = fmaf(a.w, b.w, acc);
    }
    h[(size_t)(blockIdx.x * 16 + r) * NH + f] = acc;
}

// out[d] = in[d]*dinv[d]^2 + sum_{csr[d]} in[src]*nrm   (16 lanes per node)
__global__ __launch_bounds__(256) void k_gather(const float* __restrict__ in,
                                                const float* __restrict__ dinv,
                                                const int* __restrict__ rowptr,
                                                const int2* __restrict__ csr,
                                                float* __restrict__ out, int n) {
    int tid = blockIdx.x * 256 + threadIdx.x;
    int d = tid >> 4, f = tid & 15;
    if (d >= n) return;
    float di = dinv[d];
    float acc = in[tid] * di * di;
    int e0 = rowptr[d], e1 = rowptr[d + 1];
    for (int j = e0; j < e1; ++j) {
        int2 ent = csr[j];                       // 8B broadcast across 16 lanes
        acc = fmaf(in[ent.x * NH + f], __int_as_float(ent.y), acc);
    }
    out[tid] = acc;
}

__global__ __launch_bounds__(256) void k_biasrelu(float* __restrict__ o1,
                                                  const float* __restrict__ b1, int n16) {
    int tid = blockIdx.x * 256 + threadIdx.x;
    if (tid < n16) o1[tid] = fmaxf(o1[tid] + b1[tid & 15], 0.0f);
}

// out = log_softmax(agg @ W2 + b2)
__global__ __launch_bounds__(256) void k_out(const float* __restrict__ agg,
                                             const float* __restrict__ w2,
                                             const float* __restrict__ b2,
                                             float* __restrict__ out, int n) {
    __shared__ float w2s[NH * 40];
    __shared__ float b2s[40];
    for (int t = threadIdx.x; t < NH * 40; t += 256) w2s[t] = w2[t];
    if (threadIdx.x < 40) b2s[threadIdx.x] = b2[threadIdx.x];
    __syncthreads();
    int i = blockIdx.x * 256 + threadIdx.x;
    if (i >= n) return;
    float v[NH];
    const float4* ap = (const float4*)(agg + (size_t)i * NH);
#pragma unroll
    for (int m = 0; m < 4; ++m) {
        float4 t4 = ap[m];
        v[4 * m] = t4.x; v[4 * m + 1] = t4.y; v[4 * m + 2] = t4.z; v[4 * m + 3] = t4.w;
    }
    float z[40];
#pragma unroll
    for (int c = 0; c < 40; ++c) {
        float a = b2s[c];
#pragma unroll
        for (int ff = 0; ff < NH; ++ff) a = fmaf(v[ff], w2s[ff * 40 + c], a);
        z[c] = a;
    }
    float mx = z[0];
#pragma unroll
    for (int c = 1; c < 40; ++c) mx = fmaxf(mx, z[c]);
    float sum = 0.0f;
#pragma unroll
    for (int c = 0; c < 40; ++c) sum += expf(z[c] - mx);
    float ls = mx + logf(sum);
    float4* op = (float4*)(out + (size_t)i * 40);
#pragma unroll
    for (int m = 0; m < 10; ++m) {
        float4 o;
        o.x = z[4 * m] - ls; o.y = z[4 * m + 1] - ls;
        o.z = z[4 * m + 2] - ls; o.w = z[4 * m + 3] - ls;
        op[m] = o;
    }
}

extern "C" void kernel_launch(void* const* d_in, const int* in_sizes, int n_in,
                              void* d_out, int out_size, void* d_ws, size_t ws_size,
                              hipStream_t stream) {
    const float* x  = (const float*)d_in[0];
    const int*   ei = (const int*)d_in[1];
    const float* ew = (const float*)d_in[2];
    const float* w1 = (const float*)d_in[3];
    const float* b1 = (const float*)d_in[4];
    const float* w2 = (const float*)d_in[5];
    const float* b2 = (const float*)d_in[6];
    float* out = (float*)d_out;

    int n = in_sizes[0] / NF;      // 100000
    int E = in_sizes[2];           // 3200000
    const int* src = ei;
    const int* dst = ei + E;

    float* ws     = (float*)d_ws;
    float* wdeg   = ws;                         // becomes dinv in place
    int*   ideg   = (int*)(ws + 100000);
    int*   rowptr = (int*)(ws + 200000);        // n+1
    int*   cursor = (int*)(ws + 300008);
    int*   bsum   = (int*)(ws + 400016);
    int2*  csr    = (int2*)(ws + 401024);       // 2*E ints
    float* h      = ws + 6801024;
    float* o1     = ws + 8401024;
    float* o2     = ws + 10001024;

    int nb_n   = (n + 255) / 256;               // 391
    int nb_nf  = (n * NH + 255) / 256;          // 6250
    int nb_e   = (E + 255) / 256;               // 12500

    k_init<<<nb_n, 256, 0, stream>>>(wdeg, ideg, cursor, n);
    k_count<<<nb_e, 256, 0, stream>>>(dst, ew, ideg, wdeg, E);
    k_dinv<<<nb_n, 256, 0, stream>>>(wdeg, n);
    k_scan_block<<<nb_n, 256, 0, stream>>>(ideg, rowptr, bsum, n);
    k_scan_tops<<<1, 512, 0, stream>>>(bsum, rowptr, nb_n, n);
    k_scan_add<<<nb_n, 256, 0, stream>>>(rowptr, bsum, n);
    k_fill<<<nb_e, 256, 0, stream>>>(src, dst, ew, wdeg, rowptr, cursor, csr, E);
    k_gemm1<<<n / 16, 256, 0, stream>>>(x, w1, h);
    k_gather<<<nb_nf, 256, 0, stream>>>(h, wdeg, rowptr, csr, o1, n);
    k_biasrelu<<<nb_nf, 256, 0, stream>>>(o1, b1, n * NH);
    k_gather<<<nb_nf, 256, 0, stream>>>(o1, wdeg, rowptr, csr, o2, n);
    k_out<<<nb_n, 256, 0, stream>>>(o2, w2, b2, out, n);
}

// Round 7
// 734.697 us; speedup vs baseline: 1.0170x; 1.0170x over previous
//
#include <hip/hip_runtime.h>

// GCN 2-layer, CSR-gather, REP=8 de-contended atomics.
// Round-6 post-mortem: k_count was 280us -- 6.4M atomics over only 100k
// addresses (64 concurrent/addr) => 32B/atomic write-through, 0.78 TB/s.
// prop16 (round 3) showed 51.2M atomics over 1.6M addrs run at 293 G/s with
// 4B/atomic. Fix: replicate count/cursor arrays 8x (r = tid&7) => avg 4
// edges per (r,d) slot; per-replica slot starts computed contention-free.

#define NF 512
#define NH 16
#define REP 8
#define XPAD 520

// ---- ws layout (4B units), total 11,501,056 floats = 46.0 MB ----
// dinv     @ 0        (n)
// ideg_tot @ 100000   (n)
// bsum     @ 200000   (1024)
// rowptr   @ 201024   (n+1)
// ideg_r   @ 301056   (REP*n)   counts, then converted to cursors in place
// wdeg_r   @ 1101056  (REP*n)
// csr int2 @ 1901056  (2*E)     byte off 7604224 %8==0
// h        @ 8301056  (n*16)    also holds o2 (second gather output)
// o1       @ 9901056  (n*16)

__global__ __launch_bounds__(256) void k_zero(int* __restrict__ p, int m) {
    int i = blockIdx.x * 256 + threadIdx.x;
    if (i < m) p[i] = 0;
}

__global__ __launch_bounds__(256) void k_count(const int* __restrict__ dst,
                                               const float* __restrict__ ew,
                                               int* __restrict__ ideg_r,
                                               float* __restrict__ wdeg_r,
                                               int E, int n) {
    int e = blockIdx.x * 256 + threadIdx.x;
    if (e >= E) return;
    int r = threadIdx.x & (REP - 1);
    int d = dst[e];
    atomicAdd(&ideg_r[r * n + d], 1);
    unsafeAtomicAdd(&wdeg_r[r * n + d], ew[e]);
}

// ideg_tot = sum_r counts; dinv = rsqrt(1 + sum_r wdeg)
__global__ __launch_bounds__(256) void k_reduce(const int* __restrict__ ideg_r,
                                                const float* __restrict__ wdeg_r,
                                                int* __restrict__ ideg_tot,
                                                float* __restrict__ dinv, int n) {
    int d = blockIdx.x * 256 + threadIdx.x;
    if (d >= n) return;
    int it = 0; float w = 1.0f;
#pragma unroll
    for (int r = 0; r < REP; ++r) {
        it += ideg_r[r * n + d];
        w  += wdeg_r[r * n + d];
    }
    ideg_tot[d] = it;
    dinv[d] = rsqrtf(w);
}

// exclusive scan of ideg_tot -> rowptr (verified round 6)
__global__ __launch_bounds__(256) void k_scan_block(const int* __restrict__ ideg,
                                                    int* __restrict__ rowptr,
                                                    int* __restrict__ bsum, int n) {
    __shared__ int sh[256];
    int t = threadIdx.x, g = blockIdx.x * 256 + t;
    int v = (g < n) ? ideg[g] : 0;
    sh[t] = v; __syncthreads();
    for (int off = 1; off < 256; off <<= 1) {
        int a = (t >= off) ? sh[t - off] : 0;
        __syncthreads();
        sh[t] += a;
        __syncthreads();
    }
    if (g < n) rowptr[g] = sh[t] - v;
    if (t == 255) bsum[blockIdx.x] = sh[255];
}

__global__ __launch_bounds__(512) void k_scan_tops(int* __restrict__ bsum,
                                                   int* __restrict__ rowptr,
                                                   int nb, int n) {
    __shared__ int sh[512];
    int t = threadIdx.x;
    int v = (t < nb) ? bsum[t] : 0;
    sh[t] = v; __syncthreads();
    for (int off = 1; off < 512; off <<= 1) {
        int a = (t >= off) ? sh[t - off] : 0;
        __syncthreads();
        sh[t] += a;
        __syncthreads();
    }
    if (t < nb) bsum[t] = sh[t] - v;
    if (t == 511) rowptr[n] = sh[511];     // == E
}

__global__ __launch_bounds__(256) void k_scan_add(int* __restrict__ rowptr,
                                                  const int* __restrict__ bsum, int n) {
    int i = blockIdx.x * 256 + threadIdx.x;
    if (i < n) rowptr[i] += bsum[i >> 8];
}

// convert per-replica counts -> per-replica slot starts, in place
__global__ __launch_bounds__(256) void k_cursor(int* __restrict__ ideg_r,
                                                const int* __restrict__ rowptr, int n) {
    int d = blockIdx.x * 256 + threadIdx.x;
    if (d >= n) return;
    int run = rowptr[d];
#pragma unroll
    for (int r = 0; r < REP; ++r) {
        int c = ideg_r[r * n + d];
        ideg_r[r * n + d] = run;
        run += c;
    }
}

__global__ __launch_bounds__(256) void k_fill(const int* __restrict__ src,
                                              const int* __restrict__ dst,
                                              const float* __restrict__ ew,
                                              const float* __restrict__ dinv,
                                              int* __restrict__ cursor_r,
                                              int2* __restrict__ csr, int E, int n) {
    int e = blockIdx.x * 256 + threadIdx.x;
    if (e >= E) return;
    int r = threadIdx.x & (REP - 1);
    int s = src[e], d = dst[e];
    float nrm = dinv[s] * ew[e] * dinv[d];
    int pos = atomicAdd(&cursor_r[r * n + d], 1);
    csr[pos] = make_int2(s, __float_as_int(nrm));
}

// h = x @ W1, 16 rows/block; x staged via coalesced float4; W1 in k4-blocked
// LDS layout wt[k4][f][4] -> 16-lane b128 read covers 64 consecutive floats
// (2 lanes/bank, free) with zero padding.
__global__ __launch_bounds__(256) void k_gemm1(const float* __restrict__ x,
                                               const float* __restrict__ w1,
                                               float* __restrict__ h) {
    __shared__ float xs[16 * XPAD];
    __shared__ float wt[NF * NH];
    for (int t = threadIdx.x; t < NF * NH; t += 256) {
        int k = t >> 4, f = t & 15;
        wt[(k >> 2) * 64 + (f << 2) + (k & 3)] = w1[t];
    }
    const float4* xsrc = (const float4*)(x + (size_t)blockIdx.x * 16 * NF);
#pragma unroll
    for (int s = 0; s < 8; ++s) {
        int idx = s * 256 + threadIdx.x;
        int row = idx >> 7, col4 = idx & 127;
        float4 v = xsrc[idx];
        float* p = &xs[row * XPAD + col4 * 4];
        p[0] = v.x; p[1] = v.y; p[2] = v.z; p[3] = v.w;
    }
    __syncthreads();
    int r = threadIdx.x >> 4, f = threadIdx.x & 15;
    const float4* xr = (const float4*)&xs[r * XPAD];
    const float4* wr = (const float4*)&wt[f << 2];
    float acc = 0.0f;
#pragma unroll 8
    for (int k4 = 0; k4 < NF / 4; ++k4) {
        float4 a = xr[k4], b = wr[k4 * 16];
        acc = fmaf(a.x, b.x, acc);
        acc = fmaf(a.y, b.y, acc);
        acc = fmaf(a.z, b.z, acc);
        acc = fmaf(a.w, b.w, acc);
    }
    h[(size_t)(blockIdx.x * 16 + r) * NH + f] = acc;
}

// out[d] = in[d]*dinv[d]^2 + sum_{csr row d} in[src]*nrm  (16 lanes/node)
__global__ __launch_bounds__(256) void k_gather(const float* __restrict__ in,
                                                const float* __restrict__ dinv,
                                                const int* __restrict__ rowptr,
                                                const int2* __restrict__ csr,
                                                float* __restrict__ out, int n) {
    int tid = blockIdx.x * 256 + threadIdx.x;
    int d = tid >> 4, f = tid & 15;
    if (d >= n) return;
    float di = dinv[d];
    float acc = in[tid] * di * di;
    int e0 = rowptr[d], e1 = rowptr[d + 1];
    for (int j = e0; j < e1; ++j) {
        int2 ent = csr[j];
        acc = fmaf(in[ent.x * NH + f], __int_as_float(ent.y), acc);
    }
    out[tid] = acc;
}

__global__ __launch_bounds__(256) void k_biasrelu(float* __restrict__ o1,
                                                  const float* __restrict__ b1, int n16) {
    int tid = blockIdx.x * 256 + threadIdx.x;
    if (tid < n16) o1[tid] = fmaxf(o1[tid] + b1[tid & 15], 0.0f);
}

__global__ __launch_bounds__(256) void k_out(const float* __restrict__ agg,
                                             const float* __restrict__ w2,
                                             const float* __restrict__ b2,
                                             float* __restrict__ out, int n) {
    __shared__ float w2s[NH * 40];
    __shared__ float b2s[40];
    for (int t = threadIdx.x; t < NH * 40; t += 256) w2s[t] = w2[t];
    if (threadIdx.x < 40) b2s[threadIdx.x] = b2[threadIdx.x];
    __syncthreads();
    int i = blockIdx.x * 256 + threadIdx.x;
    if (i >= n) return;
    float v[NH];
    const float4* ap = (const float4*)(agg + (size_t)i * NH);
#pragma unroll
    for (int m = 0; m < 4; ++m) {
        float4 t4 = ap[m];
        v[4 * m] = t4.x; v[4 * m + 1] = t4.y; v[4 * m + 2] = t4.z; v[4 * m + 3] = t4.w;
    }
    float z[40];
#pragma unroll
    for (int c = 0; c < 40; ++c) {
        float a = b2s[c];
#pragma unroll
        for (int ff = 0; ff < NH; ++ff) a = fmaf(v[ff], w2s[ff * 40 + c], a);
        z[c] = a;
    }
    float mx = z[0];
#pragma unroll
    for (int c = 1; c < 40; ++c) mx = fmaxf(mx, z[c]);
    float sum = 0.0f;
#pragma unroll
    for (int c = 0; c < 40; ++c) sum += expf(z[c] - mx);
    float ls = mx + logf(sum);
    float4* op = (float4*)(out + (size_t)i * 40);
#pragma unroll
    for (int m = 0; m < 10; ++m) {
        float4 o;
        o.x = z[4 * m] - ls; o.y = z[4 * m + 1] - ls;
        o.z = z[4 * m + 2] - ls; o.w = z[4 * m + 3] - ls;
        op[m] = o;
    }
}

extern "C" void kernel_launch(void* const* d_in, const int* in_sizes, int n_in,
                              void* d_out, int out_size, void* d_ws, size_t ws_size,
                              hipStream_t stream) {
    const float* x  = (const float*)d_in[0];
    const int*   ei = (const int*)d_in[1];
    const float* ew = (const float*)d_in[2];
    const float* w1 = (const float*)d_in[3];
    const float* b1 = (const float*)d_in[4];
    const float* w2 = (const float*)d_in[5];
    const float* b2 = (const float*)d_in[6];
    float* out = (float*)d_out;

    int n = in_sizes[0] / NF;      // 100000
    int E = in_sizes[2];           // 3200000
    const int* src = ei;
    const int* dst = ei + E;

    float* ws       = (float*)d_ws;
    float* dinv     = ws;                       // n
    int*   ideg_tot = (int*)(ws + 100000);      // n
    int*   bsum     = (int*)(ws + 200000);      // 1024
    int*   rowptr   = (int*)(ws + 201024);      // n+1
    int*   ideg_r   = (int*)(ws + 301056);      // REP*n (counts -> cursors)
    float* wdeg_r   = ws + 1101056;             // REP*n
    int2*  csr      = (int2*)(ws + 1901056);    // 2*E ints
    float* h        = ws + 8301056;             // n*16 (also o2)
    float* o1       = ws + 9901056;             // n*16

    int nb_n  = (n + 255) / 256;                // 391
    int nb_nf = (n * NH + 255) / 256;           // 6250
    int nb_e  = (E + 255) / 256;                // 12500
    int nrep  = 2 * REP * n;                    // ideg_r + wdeg_r contiguous
    int nb_z  = (nrep + 255) / 256;

    k_zero<<<nb_z, 256, 0, stream>>>(ideg_r, nrep);
    k_count<<<nb_e, 256, 0, stream>>>(dst, ew, ideg_r, wdeg_r, E, n);
    k_reduce<<<nb_n, 256, 0, stream>>>(ideg_r, wdeg_r, ideg_tot, dinv, n);
    k_scan_block<<<nb_n, 256, 0, stream>>>(ideg_tot, rowptr, bsum, n);
    k_scan_tops<<<1, 512, 0, stream>>>(bsum, rowptr, nb_n, n);
    k_scan_add<<<nb_n, 256, 0, stream>>>(rowptr, bsum, n);
    k_cursor<<<nb_n, 256, 0, stream>>>(ideg_r, rowptr, n);
    k_fill<<<nb_e, 256, 0, stream>>>(src, dst, ew, dinv, ideg_r, csr, E, n);
    k_gemm1<<<n / 16, 256, 0, stream>>>(x, w1, h);
    k_gather<<<nb_nf, 256, 0, stream>>>(h, dinv, rowptr, csr, o1, n);
    k_biasrelu<<<nb_nf, 256, 0, stream>>>(o1, b1, n * NH);
    k_gather<<<nb_nf, 256, 0, stream>>>(o1, dinv, rowptr, csr, h, n);
    k_out<<<nb_n, 256, 0, stream>>>(h, w2, b2, out, n);
}